// Round 5
// 185.878 us; speedup vs baseline: 1.1280x; 1.1280x over previous
//
#include <hip/hip_runtime.h>

#define SQ2F 0.70710678118654752440f

// Filter taps are compile-time constants (reference _filters() is deterministic;
// float literals round identically to np.float32). Zeros fold out of FMA chains.
static constexpr float H0O[5] = {-0.05f, 0.25f, 0.6f, 0.25f, -0.05f};
static constexpr float H1O[7] = {(float)(-3.0/280.0), (float)(3.0/56.0), (float)(73.0/280.0),
                                 (float)(-17.0/28.0), (float)(73.0/280.0), (float)(3.0/56.0),
                                 (float)(-3.0/280.0)};
static constexpr float H0A[10] = {0.03516384f, 0.0f, -0.08832942f, 0.23389032f, 0.76027237f,
                                  0.5875183f, 0.0f, -0.11430184f, 0.0f, 0.0f};
static constexpr float H0B[10] = {0.0f, 0.0f, -0.11430184f, 0.0f, 0.5875183f,
                                  0.76027237f, 0.23389032f, -0.08832942f, 0.0f, 0.03516384f};
static constexpr float H1A[10] = {0.0f, 0.0f, -0.11430184f, 0.0f, 0.5875183f,
                                  -0.76027237f, 0.23389032f, 0.08832942f, 0.0f, -0.03516384f};
static constexpr float H1B[10] = {-0.03516384f, 0.0f, 0.08832942f, 0.23389032f, -0.76027237f,
                                  0.5875183f, 0.0f, -0.11430184f, 0.0f, 0.0f};

__device__ __forceinline__ int symref(int t, int L) {
    if (t < 0) t = -1 - t;
    if (t >= L) t = 2 * L - 1 - t;
    return t;
}

// async global->LDS, 4 B per lane; lds dest must be wave-uniform base (+lane*4).
// PROVEN pattern (baseline 209.8us kernel). The 12B dwordx3 variant is NOT
// hardware-verified for its per-lane LDS stride -- it produced structural
// corruption in R1; do not reintroduce without an isolated probe.
__device__ __forceinline__ void gload_lds4(const float* g, float* lds) {
    __builtin_amdgcn_global_load_lds(
        (const __attribute__((address_space(1))) void*)g,
        (__attribute__((address_space(3))) void*)lds, 4, 0, 0);
}

__device__ __forceinline__ float2 f2add(float2 a, float2 b) { return make_float2(a.x + b.x, a.y + b.y); }
__device__ __forceinline__ float2 f2fma(float s, float2 a, float2 b) {
    return make_float2(fmaf(s, a.x, b.x), fmaf(s, a.y, b.y));
}
__device__ __forceinline__ float2 f2s(float s, float2 a) { return make_float2(s * a.x, s * a.y); }

// symmetric 7-tap (H1O) over 7 float2 samples: sum_t H1O[t]*v[6-t]
__device__ __forceinline__ float2 f2sym7(float2 a, float2 b, float2 c, float2 d,
                                         float2 e, float2 f, float2 g) {
    float2 r = f2s(H1O[3], d);
    r = f2fma(H1O[0], f2add(a, g), r);
    r = f2fma(H1O[1], f2add(b, f), r);
    r = f2fma(H1O[2], f2add(c, e), r);
    return r;
}
// symmetric 5-tap (H0O) over 5 float2 samples
__device__ __forceinline__ float2 f2sym5(float2 a, float2 b, float2 c, float2 d, float2 e) {
    float2 r = f2s(H0O[2], c);
    r = f2fma(H0O[0], f2add(a, e), r);
    r = f2fma(H0O[1], f2add(b, d), r);
    return r;
}
// symmetric 5-tap over float4 lanes (4 columns at once)
__device__ __forceinline__ float4 f4sym5(float4 a, float4 b, float4 c, float4 d, float4 e) {
    float4 r;
    r.x = fmaf(H0O[0], a.x + e.x, fmaf(H0O[1], b.x + d.x, H0O[2] * c.x));
    r.y = fmaf(H0O[0], a.y + e.y, fmaf(H0O[1], b.y + d.y, H0O[2] * c.y));
    r.z = fmaf(H0O[0], a.z + e.z, fmaf(H0O[1], b.z + d.z, H0O[2] * c.z));
    r.w = fmaf(H0O[0], a.w + e.w, fmaf(H0O[1], b.w + d.w, H0O[2] * c.w));
    return r;
}

// ---------------------------------------------------------------------------
// Fused levels 1+2. Block = 512 threads; covers x core rows [32ti,32ti+32),
// cols [64tj,64tj+64). Produces yh0 (16x32), yh1 (8x16), ll2 (16x32).
// LDS overlays (45.3 KB -> 3 blocks/CU), all pitches 16B- or 8B-friendly:
//   S[    0.. 4368) : Xs 52x84 (pitch 84) -> reused as Ls 48x84 after stage 1
//   S[ 4368.. 8736) : Los 52x84 -> after stage 2a, LO2/HI2 48x34 each
//   S[ 8736..11320) : His 38x68
// All vector LDS ops keep lane -> bank-quad histograms uniform:
//   pitch 84: quad = (21r+slot)%8 = (5r+slot)%8 cycles all 8 as r or slot runs;
//   pitch 68: (17r+s)%8 = (r+s)%8; pitch 34 float2 pairs: (17r+cp)%16 = (r+cp)%16.
// The +/-8 halo baked in at staging IS the symmetric extension: symmetric
// filters in the factored (a+e)*h0 form make reflected windows bit-exact
// (fp add commutativity), so stages 2-4 never need reflection paths.
// ---------------------------------------------------------------------------
#define XS(r,c)  S[(r)*84 + (c)]
#define LS(r,c)  S[(r)*84 + (c)]
#define LOS(r,c) S[4368 + (r)*84 + (c)]
#define LO2(r,c) S[4368 + (r)*34 + (c)]
#define HI2(r,c) S[6000 + (r)*34 + (c)]
#define HIS(r,c) S[8736 + (r)*68 + (c)]

__global__ __launch_bounds__(512) void dtcwt_l12(
    const float* __restrict__ x,
    float* __restrict__ yh0,
    float* __restrict__ yh1,
    float* __restrict__ ll2)
{
    __shared__ __align__(16) float S[11320];
    int tid = threadIdx.x, bx = blockIdx.x;
    int tj = bx & 3, ti = (bx >> 2) & 7, bc = bx >> 5;
    const int xr0 = 32 * ti - 10, xc0 = 64 * tj - 10;
    const float* xb = x + (size_t)bc * 65536;
    const int lane = tid & 63;

    // ---- stage 0: async DMA of 52x84 x-region into Xs (contiguous, pitch 84)
    // Baseline-proven 4B-per-lane pattern.
    const bool interior0 = (ti >= 1) && (ti <= 6) && (tj >= 1) && (tj <= 2);
    if (interior0) {
        for (int p = tid; p < 4368; p += 512) {
            int r = p / 84, c = p - r * 84;
            gload_lds4(xb + (xr0 + r) * 256 + (xc0 + c), &S[p - lane]);
        }
    } else {
        for (int p = tid; p < 4368; p += 512) {
            int r = p / 84, c = p - r * 84;
            gload_lds4(xb + symref(xr0 + r, 256) * 256 + symref(xc0 + c, 256),
                       &S[p - lane]);
        }
    }
    __syncthreads();   // drains vmcnt for the DMA

    // ---- stage 1: row filters, 8 outputs/thread, b128 LDS I/O, symmetric taps
    for (int p = tid; p < 520; p += 512) {                  // 52 rows x 10 slots
        int r = p / 10, s = p - r * 10, c8 = 8 * s;
        const float* xr = &XS(r, c8);
        float4 q0 = *(const float4*)&xr[0];
        float4 q1 = *(const float4*)&xr[4];
        float4 q2 = *(const float4*)&xr[8];
        float u[12] = {q0.x,q0.y,q0.z,q0.w, q1.x,q1.y,q1.z,q1.w, q2.x,q2.y,q2.z,q2.w};
        float l[8];
        #pragma unroll
        for (int j = 0; j < 8; j++)
            l[j] = fmaf(H0O[0], u[j] + u[j+4],
                   fmaf(H0O[1], u[j+1] + u[j+3], H0O[2] * u[j+2]));
        *(float4*)&LOS(r, c8)     = make_float4(l[0], l[1], l[2], l[3]);
        *(float4*)&LOS(r, c8 + 4) = make_float4(l[4], l[5], l[6], l[7]);
    }
    for (int p = tid; p < 304; p += 512) {                  // 38 rows x 8 slots
        int r = p >> 3, s = p & 7, c8 = 8 * s;
        const float* xr = &XS(r + 7, c8 + 4);
        float4 q0 = *(const float4*)&xr[0];
        float4 q1 = *(const float4*)&xr[4];
        float4 q2 = *(const float4*)&xr[8];
        float4 q3 = *(const float4*)&xr[12];
        float4 q4 = *(const float4*)&xr[16];
        float w[20] = {q0.x,q0.y,q0.z,q0.w, q1.x,q1.y,q1.z,q1.w, q2.x,q2.y,q2.z,q2.w,
                       q3.x,q3.y,q3.z,q3.w, q4.x,q4.y,q4.z,q4.w};
        float h[8];
        #pragma unroll
        for (int j = 0; j < 8; j++)
            h[j] = fmaf(H1O[0], w[j+3] + w[j+9],
                   fmaf(H1O[1], w[j+4] + w[j+8],
                   fmaf(H1O[2], w[j+5] + w[j+7], H1O[3] * w[j+6])));
        *(float4*)&HIS(r, c8)     = make_float4(h[0], h[1], h[2], h[3]);
        *(float4*)&HIS(r, c8 + 4) = make_float4(h[4], h[5], h[6], h[7]);
    }
    __syncthreads();

    // ---- stage 2b: ll tile, 2 rows x 4 cols per thread, b128 I/O
    for (int p = tid; p < 480; p += 512) {                  // 24 rowpairs x 20 slots
        int rp = p / 20, s = p - rp * 20, c4 = 4 * s;
        const float* l0 = &LOS(2 * rp, c4);
        float4 m0 = *(const float4*)&l0[0];
        float4 m1 = *(const float4*)&l0[84];
        float4 m2 = *(const float4*)&l0[168];
        float4 m3 = *(const float4*)&l0[252];
        float4 m4 = *(const float4*)&l0[336];
        float4 m5 = *(const float4*)&l0[420];
        *(float4*)&LS(2 * rp,     c4) = f4sym5(m0, m1, m2, m3, m4);
        *(float4*)&LS(2 * rp + 1, c4) = f4sym5(m1, m2, m3, m4, m5);
    }
    // ---- stage 2a: yh0, col-pair per thread (b64 reads), in-thread q2c, no shfl
    {
        float* yb = yh0 + (size_t)bc * 196608;
        const size_t bs = 32768;
        int cp = tid & 31, oi = tid >> 5;                   // 32 colpairs x 16 oi
        float2 low[8], hiw[8];
        #pragma unroll
        for (int k = 0; k < 8; k++) {
            low[k] = *(const float2*)&LOS(2 * oi + 7 + k, 2 * cp + 8);
            hiw[k] = *(const float2*)&HIS(2 * oi + k,     2 * cp);
        }
        float2 lhe = f2s(SQ2F, f2sym7(low[0],low[1],low[2],low[3],low[4],low[5],low[6]));
        float2 lho = f2s(SQ2F, f2sym7(low[1],low[2],low[3],low[4],low[5],low[6],low[7]));
        float2 hhe = f2s(SQ2F, f2sym7(hiw[0],hiw[1],hiw[2],hiw[3],hiw[4],hiw[5],hiw[6]));
        float2 hho = f2s(SQ2F, f2sym7(hiw[1],hiw[2],hiw[3],hiw[4],hiw[5],hiw[6],hiw[7]));
        float2 hle = f2s(SQ2F, f2sym5(hiw[1],hiw[2],hiw[3],hiw[4],hiw[5]));
        float2 hlo = f2s(SQ2F, f2sym5(hiw[2],hiw[3],hiw[4],hiw[5],hiw[6]));
        int i0 = 16 * ti + oi, j0 = 32 * tj + cp;
        size_t pix = ((size_t)i0 * 128 + j0) * 2;
        // q2c: a=e.x b=e.y c=o.x d=o.y -> band k (a-d,b+c), band 5-k (a+d,b-c)
        { float a=lhe.x, b=lhe.y, c=lho.x, d=lho.y;
          *(float2*)&yb[0*bs + pix] = make_float2(a-d, b+c);
          *(float2*)&yb[5*bs + pix] = make_float2(a+d, b-c); }
        { float a=hhe.x, b=hhe.y, c=hho.x, d=hho.y;
          *(float2*)&yb[1*bs + pix] = make_float2(a-d, b+c);
          *(float2*)&yb[4*bs + pix] = make_float2(a+d, b-c); }
        { float a=hle.x, b=hle.y, c=hlo.x, d=hlo.y;
          *(float2*)&yb[2*bs + pix] = make_float2(a-d, b+c);
          *(float2*)&yb[3*bs + pix] = make_float2(a+d, b-c); }
    }
    __syncthreads();

    // ---- stage 3: rowdfilt on Ls -> LO2/HI2. b128 window reads; halo in Ls
    // is bit-exactly the symmetric extension, so no reflection path needed.
    for (int p = tid; p < 768; p += 512) {                  // 16 n x 48 rows
        int nl = p / 48, r = p - nl * 48;
        const float* lsr = &LS(r, 4 * nl);
        float4 q0 = *(const float4*)&lsr[0];
        float4 q1 = *(const float4*)&lsr[4];
        float4 q2 = *(const float4*)&lsr[8];
        float4 q3 = *(const float4*)&lsr[12];
        float4 q4 = *(const float4*)&lsr[16];
        float v[20] = {q0.x,q0.y,q0.z,q0.w, q1.x,q1.y,q1.z,q1.w, q2.x,q2.y,q2.z,q2.w,
                       q3.x,q3.y,q3.z,q3.w, q4.x,q4.y,q4.z,q4.w};
        float aLo = 0.f, bLo = 0.f, aHi = 0.f, bHi = 0.f;
        #pragma unroll
        for (int t = 0; t < 10; t++) {
            float vo = v[19 - 2*t], ve = v[18 - 2*t];
            aLo = fmaf(H0B[t], vo, aLo); bLo = fmaf(H0A[t], ve, bLo);
            aHi = fmaf(H1B[t], vo, aHi); bHi = fmaf(H1A[t], ve, bHi);
        }
        *(float2*)&LO2(r, 2*nl) = make_float2(aLo, bLo);   // lowpass : ev=a, od=b
        *(float2*)&HI2(r, 2*nl) = make_float2(bHi, aHi);   // highpass: ev=b, od=a
    }
    __syncthreads();

    // ---- stage 4: coldfilt + q2c -> yh1, ll2. Col-pair per thread (b64),
    // LO2 half (ll+lh) on tid<128, HI2 half (hl+hh) on tid 128..255.
    if (tid < 256) {
        int half = tid >> 7, q = tid & 127;
        int cp = q & 15, li = q >> 4;                       // 16 colpairs x 8 li
        int i1 = 8 * ti + li;
        const float* Bp = half ? &HI2(0, 0) : &LO2(0, 0);
        float2 v[20];
        #pragma unroll
        for (int k = 0; k < 20; k++)
            v[k] = *(const float2*)&Bp[(4 * li + k) * 34 + 2 * cp];
        float2 z = make_float2(0.f, 0.f);
        float2 aA = z, bA = z, aB = z, bB = z;              // A: H0 pair, B: H1 pair
        #pragma unroll
        for (int t = 0; t < 10; t++) {
            float2 vo = v[19 - 2*t], ve = v[18 - 2*t];
            aA = f2fma(H0B[t], vo, aA); bA = f2fma(H0A[t], ve, bA);
            aB = f2fma(H1B[t], vo, aB); bB = f2fma(H1A[t], ve, bB);
        }
        float* yb = yh1 + (size_t)bc * 49152;
        int j1 = 16 * tj + cp;
        size_t pix = ((size_t)i1 * 64 + j1) * 2;
        const size_t bs = 8192;
        if (half == 0) {
            float* llb = ll2 + (size_t)bc * 16384;
            int gc = 32 * tj + 2 * cp;
            *(float2*)&llb[(size_t)(2*i1)     * 128 + gc] = aA;   // ll ev=a
            *(float2*)&llb[(size_t)(2*i1 + 1) * 128 + gc] = bA;   // ll od=b
            float a = SQ2F*bB.x, b = SQ2F*bB.y, c = SQ2F*aB.x, d = SQ2F*aB.y; // lh ev=b,od=a
            *(float2*)&yb[0*bs + pix] = make_float2(a-d, b+c);
            *(float2*)&yb[5*bs + pix] = make_float2(a+d, b-c);
        } else {
            float a = SQ2F*bB.x, b = SQ2F*bB.y, c = SQ2F*aB.x, d = SQ2F*aB.y; // hh ev=b,od=a
            *(float2*)&yb[1*bs + pix] = make_float2(a-d, b+c);
            *(float2*)&yb[4*bs + pix] = make_float2(a+d, b-c);
            a = SQ2F*aA.x; b = SQ2F*aA.y; c = SQ2F*bA.x; d = SQ2F*bA.y;       // hl ev=a,od=b
            *(float2*)&yb[2*bs + pix] = make_float2(a-d, b+c);
            *(float2*)&yb[3*bs + pix] = make_float2(a+d, b-c);
        }
    }
}

// ---------------------------------------------------------------------------
// Level 3: rowdfilt + coldfilt x4 + bands, vectorized the same way.
// ---------------------------------------------------------------------------
__global__ __launch_bounds__(256) void level_fused(
    const float* __restrict__ X,
    float* __restrict__ llout,
    float* __restrict__ yh,
    int R, int C, int nbi, int nbj)
{
    __shared__ __align__(16) float Xs[80 * 84];
    __shared__ __align__(16) float Lo[80 * 34];
    __shared__ __align__(16) float Hi[80 * 34];

    int tid = threadIdx.x;
    int bx  = blockIdx.x;
    int tj = bx % nbj; int ti = (bx / nbj) % nbi; int bc = bx / (nbj * nbi);
    int i0 = ti * 16, j0 = tj * 16;
    int gr0 = 4 * i0 - 8, gc0 = 4 * j0 - 8;
    const float* Xb = X + (size_t)bc * R * C;

    // staging: vector-load the in-bounds column span (16B aligned for our
    // launch params), scalar-reflect the rest; rows symref'd per row.
    // 256 threads = 8 groups of 32 lanes -> row stride MUST be 8 (10 rows/group).
    // (R4 bug: stride 16 left half the rows unstaged.)
    int cl = (gc0 < 0) ? -gc0 : 0;
    int cr = (gc0 + 80 > C) ? (C - gc0) : 80;
    int nq = (cr - cl) >> 2;                                 // 18 or 20
    for (int r = tid >> 5; r < 80; r += 8) {
        const float* rowp = Xb + (size_t)symref(gr0 + r, R) * C;
        int q = tid & 31;
        if (q < nq)
            *(float4*)&Xs[r * 84 + cl + 4 * q] =
                *(const float4*)&rowp[gc0 + cl + 4 * q];
    }
    for (int r = tid; r < 80; r += 256) {                    // leftover cols
        const float* rowp = Xb + (size_t)symref(gr0 + r, R) * C;
        for (int c = 0; c < cl; c++)  Xs[r * 84 + c] = rowp[symref(gc0 + c, C)];
        for (int c = cr; c < 80; c++) Xs[r * 84 + c] = rowp[symref(gc0 + c, C)];
    }
    __syncthreads();

    // rowdfilt: b128 window reads, float2 writes
    for (int p = tid; p < 1280; p += 256) {                  // 16 n x 80 rows
        int nl = p / 80, r = p - nl * 80;
        const float* xr = &Xs[r * 84 + 4 * nl];
        float4 q0 = *(const float4*)&xr[0];
        float4 q1 = *(const float4*)&xr[4];
        float4 q2 = *(const float4*)&xr[8];
        float4 q3 = *(const float4*)&xr[12];
        float4 q4 = *(const float4*)&xr[16];
        float v[20] = {q0.x,q0.y,q0.z,q0.w, q1.x,q1.y,q1.z,q1.w, q2.x,q2.y,q2.z,q2.w,
                       q3.x,q3.y,q3.z,q3.w, q4.x,q4.y,q4.z,q4.w};
        float aLo = 0.f, bLo = 0.f, aHi = 0.f, bHi = 0.f;
        #pragma unroll
        for (int t = 0; t < 10; t++) {
            float vo = v[19 - 2*t], ve = v[18 - 2*t];
            aLo = fmaf(H0B[t], vo, aLo); bLo = fmaf(H0A[t], ve, bLo);
            aHi = fmaf(H1B[t], vo, aHi); bHi = fmaf(H1A[t], ve, bHi);
        }
        *(float2*)&Lo[r * 34 + 2 * nl] = make_float2(aLo, bLo);
        *(float2*)&Hi[r * 34 + 2 * nl] = make_float2(bHi, aHi);
    }
    __syncthreads();

    // coldfilt + bands: col-pair per thread via b64 reads, in-thread q2c
    int R4 = R >> 2, Wq = C >> 2, C2 = C >> 1;
    int lj = tid & 15, li = tid >> 4;
    int i = i0 + li, j = j0 + lj;

    float2 vl[20], vh[20];
    #pragma unroll
    for (int k = 0; k < 20; k++) {
        vl[k] = *(const float2*)&Lo[(4 * li + k) * 34 + 2 * lj];
        vh[k] = *(const float2*)&Hi[(4 * li + k) * 34 + 2 * lj];
    }
    float2 z = make_float2(0.f, 0.f);
    float2 a_ll = z, b_ll = z, a_lh = z, b_lh = z;
    float2 a_hl = z, b_hl = z, a_hh = z, b_hh = z;
    #pragma unroll
    for (int t = 0; t < 10; t++) {
        float2 vo_l = vl[19 - 2*t], ve_l = vl[18 - 2*t];
        float2 vo_h = vh[19 - 2*t], ve_h = vh[18 - 2*t];
        a_ll = f2fma(H0B[t], vo_l, a_ll); b_ll = f2fma(H0A[t], ve_l, b_ll);
        a_lh = f2fma(H1B[t], vo_l, a_lh); b_lh = f2fma(H1A[t], ve_l, b_lh);
        a_hl = f2fma(H0B[t], vo_h, a_hl); b_hl = f2fma(H0A[t], ve_h, b_hl);
        a_hh = f2fma(H1B[t], vo_h, a_hh); b_hh = f2fma(H1A[t], ve_h, b_hh);
    }

    float* llb = llout + (size_t)bc * (R >> 1) * C2;
    *(float2*)&llb[(size_t)(2*i)   * C2 + 2*j] = a_ll;      // ll ev=a
    *(float2*)&llb[(size_t)(2*i+1) * C2 + 2*j] = b_ll;      // ll od=b

    float* yb = yh + (size_t)bc * 6 * R4 * Wq * 2;
    size_t pix = ((size_t)i * Wq + j) * 2;
    size_t bs  = (size_t)R4 * Wq * 2;
    { float a = SQ2F*b_lh.x, b = SQ2F*b_lh.y, c = SQ2F*a_lh.x, d = SQ2F*a_lh.y;
      *(float2*)&yb[0*bs + pix] = make_float2(a-d, b+c);
      *(float2*)&yb[5*bs + pix] = make_float2(a+d, b-c); }
    { float a = SQ2F*b_hh.x, b = SQ2F*b_hh.y, c = SQ2F*a_hh.x, d = SQ2F*a_hh.y;
      *(float2*)&yb[1*bs + pix] = make_float2(a-d, b+c);
      *(float2*)&yb[4*bs + pix] = make_float2(a+d, b-c); }
    { float a = SQ2F*a_hl.x, b = SQ2F*a_hl.y, c = SQ2F*b_hl.x, d = SQ2F*b_hl.y;
      *(float2*)&yb[2*bs + pix] = make_float2(a-d, b+c);
      *(float2*)&yb[3*bs + pix] = make_float2(a+d, b-c); }
}

extern "C" void kernel_launch(void* const* d_in, const int* in_sizes, int n_in,
                              void* d_out, int out_size, void* d_ws, size_t ws_size,
                              hipStream_t stream) {
    const float* x = (const float*)d_in[0];
    float* out = (float*)d_out;

    const int BC = 8 * 16;  // 128

    float* out_ll  = out;                        // 128*64*64
    float* out_yh0 = out + 524288;               // 128*6*128*128*2
    float* out_yh1 = out + 25690112;             // 128*6*64*64*2
    float* out_yh2 = out + 31981568;             // 128*6*32*32*2

    float* ll2 = (float*)d_ws;                   // 128*128*128 floats = 8 MiB

    // fused levels 1+2: x -> yh0, yh1, ll2
    dtcwt_l12<<<BC * 32, 512, 0, stream>>>(x, out_yh0, out_yh1, ll2);

    // level 3: ll2(128x128) -> yh2, final ll(64x64)
    level_fused<<<BC * 4, 256, 0, stream>>>(ll2, out_ll, out_yh2, 128, 128, 2, 2);
}

// Round 6
// 183.499 us; speedup vs baseline: 1.1427x; 1.0130x over previous
//
#include <hip/hip_runtime.h>

#define SQ2F 0.70710678118654752440f

// Filter taps are compile-time constants (reference _filters() is deterministic;
// float literals round identically to np.float32). Zeros fold out of FMA chains.
static constexpr float H0O[5] = {-0.05f, 0.25f, 0.6f, 0.25f, -0.05f};
static constexpr float H1O[7] = {(float)(-3.0/280.0), (float)(3.0/56.0), (float)(73.0/280.0),
                                 (float)(-17.0/28.0), (float)(73.0/280.0), (float)(3.0/56.0),
                                 (float)(-3.0/280.0)};
static constexpr float H0A[10] = {0.03516384f, 0.0f, -0.08832942f, 0.23389032f, 0.76027237f,
                                  0.5875183f, 0.0f, -0.11430184f, 0.0f, 0.0f};
static constexpr float H0B[10] = {0.0f, 0.0f, -0.11430184f, 0.0f, 0.5875183f,
                                  0.76027237f, 0.23389032f, -0.08832942f, 0.0f, 0.03516384f};
static constexpr float H1A[10] = {0.0f, 0.0f, -0.11430184f, 0.0f, 0.5875183f,
                                  -0.76027237f, 0.23389032f, 0.08832942f, 0.0f, -0.03516384f};
static constexpr float H1B[10] = {-0.03516384f, 0.0f, 0.08832942f, 0.23389032f, -0.76027237f,
                                  0.5875183f, 0.0f, -0.11430184f, 0.0f, 0.0f};

__device__ __forceinline__ int symref(int t, int L) {
    if (t < 0) t = -1 - t;
    if (t >= L) t = 2 * L - 1 - t;
    return t;
}

// async global->LDS, 16 B (dwordx4) per lane — the HW-VERIFIED wide variant
// (m97: emits global_load_lds_dwordx4; lane l writes lds_base + l*16).
// Requirements: wave-uniform LDS base, 16B-aligned global address, all lanes
// active. (The 12B variant corrupted data in R1 — never use it.)
__device__ __forceinline__ void gload_lds16(const float* g, float* lds) {
    __builtin_amdgcn_global_load_lds(
        (const __attribute__((address_space(1))) void*)g,
        (__attribute__((address_space(3))) void*)lds, 16, 0, 0);
}

__device__ __forceinline__ float2 f2add(float2 a, float2 b) { return make_float2(a.x + b.x, a.y + b.y); }
__device__ __forceinline__ float2 f2fma(float s, float2 a, float2 b) {
    return make_float2(fmaf(s, a.x, b.x), fmaf(s, a.y, b.y));
}
__device__ __forceinline__ float2 f2s(float s, float2 a) { return make_float2(s * a.x, s * a.y); }

// symmetric 7-tap (H1O) over 7 float2 samples: sum_t H1O[t]*v[6-t]
__device__ __forceinline__ float2 f2sym7(float2 a, float2 b, float2 c, float2 d,
                                         float2 e, float2 f, float2 g) {
    float2 r = f2s(H1O[3], d);
    r = f2fma(H1O[0], f2add(a, g), r);
    r = f2fma(H1O[1], f2add(b, f), r);
    r = f2fma(H1O[2], f2add(c, e), r);
    return r;
}
// symmetric 5-tap (H0O) over 5 float2 samples
__device__ __forceinline__ float2 f2sym5(float2 a, float2 b, float2 c, float2 d, float2 e) {
    float2 r = f2s(H0O[2], c);
    r = f2fma(H0O[0], f2add(a, e), r);
    r = f2fma(H0O[1], f2add(b, d), r);
    return r;
}
// symmetric 5-tap over float4 lanes (4 columns at once)
__device__ __forceinline__ float4 f4sym5(float4 a, float4 b, float4 c, float4 d, float4 e) {
    float4 r;
    r.x = fmaf(H0O[0], a.x + e.x, fmaf(H0O[1], b.x + d.x, H0O[2] * c.x));
    r.y = fmaf(H0O[0], a.y + e.y, fmaf(H0O[1], b.y + d.y, H0O[2] * c.y));
    r.z = fmaf(H0O[0], a.z + e.z, fmaf(H0O[1], b.z + d.z, H0O[2] * c.z));
    r.w = fmaf(H0O[0], a.w + e.w, fmaf(H0O[1], b.w + d.w, H0O[2] * c.w));
    return r;
}

// ---------------------------------------------------------------------------
// Fused levels 1+2. Block = 512 threads; covers x core rows [32ti,32ti+32),
// cols [64tj,64tj+64). Produces yh0 (16x32), yh1 (8x16), ll2 (16x32).
// LDS overlays (46.9 KB -> 3 blocks/CU):
//   S[    0.. 4784) : Xs 52x92 (pitch 92, col base 64tj-12: 16B-aligned DMA)
//                     -> reused as Ls 48x84 after stage 1
//   S[ 4784.. 9152) : Los 52x84 -> after stage 2a, LO2/HI2 48x34 each
//   S[ 9152..11736) : His 38x68
// Pitch 92 = 23 quads (odd) keeps lane->bank-quad histograms uniform for the
// lanes-vary-row reads (5r+... mod 8 covers all quads); pitch 88 would alias
// to 4 even quads (2x conflict) — do not "simplify" the pitch.
// Staging: ONE path for all blocks — 16B DMA with per-lane row symref
// (rows contiguous) + column clamp; the 16 column-border blocks then fix
// their 12/16 edge columns by LDS reflection copy (sources are in-tile).
// The halo IS the symmetric extension (factored symmetric FMA forms make
// reflected windows bit-exact), so stages 2-4 never reflect.
// ---------------------------------------------------------------------------
#define XS(r,c)  S[(r)*92 + (c)]
#define LS(r,c)  S[(r)*84 + (c)]
#define LOS(r,c) S[4784 + (r)*84 + (c)]
#define LO2(r,c) S[4784 + (r)*34 + (c)]
#define HI2(r,c) S[6416 + (r)*34 + (c)]
#define HIS(r,c) S[9152 + (r)*68 + (c)]

__global__ __launch_bounds__(512) void dtcwt_l12(
    const float* __restrict__ x,
    float* __restrict__ yh0,
    float* __restrict__ yh1,
    float* __restrict__ ll2)
{
    __shared__ __align__(16) float S[11736];
    int tid = threadIdx.x, bx = blockIdx.x;
    int tj = bx & 3, ti = (bx >> 2) & 7, bc = bx >> 5;
    const int xr0 = 32 * ti - 10, xc0 = 64 * tj - 12;   // col base ALIGNED (-12)
    const float* xb = x + (size_t)bc * 65536;
    const int lane = tid & 63;

    // ---- stage 0: 16B-DMA of the 52x92 tile. 1196 real units padded to 1536
    // (3 full iterations, all lanes always active). Padded units (r<=66) have
    // valid symref'd rows and clamped cols; they write S[4784..6144) (Los),
    // which stage 1 overwrites before any read (Los cols 80..83 never read).
    for (int u = tid; u < 1536; u += 512) {
        int r = u / 23, q = u - 23 * r;
        int rr = symref(xr0 + r, 256);                  // r<=66 -> arg<=280<512 ok
        int g  = xc0 + 4 * q;
        g = (g < 0) ? 0 : ((g > 252) ? 252 : g);        // stays 16B-aligned
        gload_lds16(xb + (size_t)rr * 256 + g, &S[4 * (u - lane)]);
    }
    __syncthreads();   // drains vmcnt for the DMA

    // column-border blocks: reflect edge cols from in-tile sources (LDS->LDS).
    // tj=0: tile c<->global c-12; c in [0,12) <- reflect: src tile col 23-c.
    // tj=3: tile c<->global 180+c; c in [76,92) <- src tile col 151-c (60..75).
    if (tj == 0) {
        for (int p = tid; p < 624; p += 512) {          // 52 x 12
            int r = p / 12, c = p - 12 * r;
            S[r * 92 + c] = S[r * 92 + (23 - c)];
        }
        __syncthreads();
    } else if (tj == 3) {
        for (int p = tid; p < 832; p += 512) {          // 52 x 16
            int r = p >> 4, c = 76 + (p & 15);
            S[r * 92 + c] = S[r * 92 + (151 - c)];
        }
        __syncthreads();
    }

    // ---- stage 1: row filters, 8 outputs/thread, b128 LDS I/O, symmetric taps
    // (windows shifted +2 vs the base-(-10) layout: lo uses u[j+2..j+6])
    for (int p = tid; p < 520; p += 512) {                  // 52 rows x 10 slots
        int r = p / 10, s = p - r * 10, c8 = 8 * s;
        const float* xr = &XS(r, c8);
        float4 q0 = *(const float4*)&xr[0];
        float4 q1 = *(const float4*)&xr[4];
        float4 q2 = *(const float4*)&xr[8];
        float4 q3 = *(const float4*)&xr[12];
        float u[16] = {q0.x,q0.y,q0.z,q0.w, q1.x,q1.y,q1.z,q1.w,
                       q2.x,q2.y,q2.z,q2.w, q3.x,q3.y,q3.z,q3.w};
        float l[8];
        #pragma unroll
        for (int j = 0; j < 8; j++)
            l[j] = fmaf(H0O[0], u[j+2] + u[j+6],
                   fmaf(H0O[1], u[j+3] + u[j+5], H0O[2] * u[j+4]));
        *(float4*)&LOS(r, c8)     = make_float4(l[0], l[1], l[2], l[3]);
        *(float4*)&LOS(r, c8 + 4) = make_float4(l[4], l[5], l[6], l[7]);
    }
    // hi: window w[j+1..j+7] from 4 quads at c8+8 (was 5 quads at base -10)
    for (int p = tid; p < 304; p += 512) {                  // 38 rows x 8 slots
        int r = p >> 3, s = p & 7, c8 = 8 * s;
        const float* xr = &XS(r + 7, c8 + 8);
        float4 q0 = *(const float4*)&xr[0];
        float4 q1 = *(const float4*)&xr[4];
        float4 q2 = *(const float4*)&xr[8];
        float4 q3 = *(const float4*)&xr[12];
        float w[16] = {q0.x,q0.y,q0.z,q0.w, q1.x,q1.y,q1.z,q1.w,
                       q2.x,q2.y,q2.z,q2.w, q3.x,q3.y,q3.z,q3.w};
        float h[8];
        #pragma unroll
        for (int j = 0; j < 8; j++)
            h[j] = fmaf(H1O[0], w[j+1] + w[j+7],
                   fmaf(H1O[1], w[j+2] + w[j+6],
                   fmaf(H1O[2], w[j+3] + w[j+5], H1O[3] * w[j+4])));
        *(float4*)&HIS(r, c8)     = make_float4(h[0], h[1], h[2], h[3]);
        *(float4*)&HIS(r, c8 + 4) = make_float4(h[4], h[5], h[6], h[7]);
    }
    __syncthreads();

    // ---- stage 2b: ll tile, 2 rows x 4 cols per thread, b128 I/O
    for (int p = tid; p < 480; p += 512) {                  // 24 rowpairs x 20 slots
        int rp = p / 20, s = p - rp * 20, c4 = 4 * s;
        const float* l0 = &LOS(2 * rp, c4);
        float4 m0 = *(const float4*)&l0[0];
        float4 m1 = *(const float4*)&l0[84];
        float4 m2 = *(const float4*)&l0[168];
        float4 m3 = *(const float4*)&l0[252];
        float4 m4 = *(const float4*)&l0[336];
        float4 m5 = *(const float4*)&l0[420];
        *(float4*)&LS(2 * rp,     c4) = f4sym5(m0, m1, m2, m3, m4);
        *(float4*)&LS(2 * rp + 1, c4) = f4sym5(m1, m2, m3, m4, m5);
    }
    // ---- stage 2a: yh0, col-pair per thread (b64 reads), in-thread q2c, no shfl
    {
        float* yb = yh0 + (size_t)bc * 196608;
        const size_t bs = 32768;
        int cp = tid & 31, oi = tid >> 5;                   // 32 colpairs x 16 oi
        float2 low[8], hiw[8];
        #pragma unroll
        for (int k = 0; k < 8; k++) {
            low[k] = *(const float2*)&LOS(2 * oi + 7 + k, 2 * cp + 8);
            hiw[k] = *(const float2*)&HIS(2 * oi + k,     2 * cp);
        }
        float2 lhe = f2s(SQ2F, f2sym7(low[0],low[1],low[2],low[3],low[4],low[5],low[6]));
        float2 lho = f2s(SQ2F, f2sym7(low[1],low[2],low[3],low[4],low[5],low[6],low[7]));
        float2 hhe = f2s(SQ2F, f2sym7(hiw[0],hiw[1],hiw[2],hiw[3],hiw[4],hiw[5],hiw[6]));
        float2 hho = f2s(SQ2F, f2sym7(hiw[1],hiw[2],hiw[3],hiw[4],hiw[5],hiw[6],hiw[7]));
        float2 hle = f2s(SQ2F, f2sym5(hiw[1],hiw[2],hiw[3],hiw[4],hiw[5]));
        float2 hlo = f2s(SQ2F, f2sym5(hiw[2],hiw[3],hiw[4],hiw[5],hiw[6]));
        int i0 = 16 * ti + oi, j0 = 32 * tj + cp;
        size_t pix = ((size_t)i0 * 128 + j0) * 2;
        // q2c: a=e.x b=e.y c=o.x d=o.y -> band k (a-d,b+c), band 5-k (a+d,b-c)
        { float a=lhe.x, b=lhe.y, c=lho.x, d=lho.y;
          *(float2*)&yb[0*bs + pix] = make_float2(a-d, b+c);
          *(float2*)&yb[5*bs + pix] = make_float2(a+d, b-c); }
        { float a=hhe.x, b=hhe.y, c=hho.x, d=hho.y;
          *(float2*)&yb[1*bs + pix] = make_float2(a-d, b+c);
          *(float2*)&yb[4*bs + pix] = make_float2(a+d, b-c); }
        { float a=hle.x, b=hle.y, c=hlo.x, d=hlo.y;
          *(float2*)&yb[2*bs + pix] = make_float2(a-d, b+c);
          *(float2*)&yb[3*bs + pix] = make_float2(a+d, b-c); }
    }
    __syncthreads();

    // ---- stage 3: rowdfilt on Ls -> LO2/HI2. b128 window reads; halo in Ls
    // is bit-exactly the symmetric extension, so no reflection path needed.
    for (int p = tid; p < 768; p += 512) {                  // 16 n x 48 rows
        int nl = p / 48, r = p - nl * 48;
        const float* lsr = &LS(r, 4 * nl);
        float4 q0 = *(const float4*)&lsr[0];
        float4 q1 = *(const float4*)&lsr[4];
        float4 q2 = *(const float4*)&lsr[8];
        float4 q3 = *(const float4*)&lsr[12];
        float4 q4 = *(const float4*)&lsr[16];
        float v[20] = {q0.x,q0.y,q0.z,q0.w, q1.x,q1.y,q1.z,q1.w, q2.x,q2.y,q2.z,q2.w,
                       q3.x,q3.y,q3.z,q3.w, q4.x,q4.y,q4.z,q4.w};
        float aLo = 0.f, bLo = 0.f, aHi = 0.f, bHi = 0.f;
        #pragma unroll
        for (int t = 0; t < 10; t++) {
            float vo = v[19 - 2*t], ve = v[18 - 2*t];
            aLo = fmaf(H0B[t], vo, aLo); bLo = fmaf(H0A[t], ve, bLo);
            aHi = fmaf(H1B[t], vo, aHi); bHi = fmaf(H1A[t], ve, bHi);
        }
        *(float2*)&LO2(r, 2*nl) = make_float2(aLo, bLo);   // lowpass : ev=a, od=b
        *(float2*)&HI2(r, 2*nl) = make_float2(bHi, aHi);   // highpass: ev=b, od=a
    }
    __syncthreads();

    // ---- stage 4: coldfilt + q2c -> yh1, ll2. Col-pair per thread (b64),
    // LO2 half (ll+lh) on tid<128, HI2 half (hl+hh) on tid 128..255.
    if (tid < 256) {
        int half = tid >> 7, q = tid & 127;
        int cp = q & 15, li = q >> 4;                       // 16 colpairs x 8 li
        int i1 = 8 * ti + li;
        const float* Bp = half ? &HI2(0, 0) : &LO2(0, 0);
        float2 v[20];
        #pragma unroll
        for (int k = 0; k < 20; k++)
            v[k] = *(const float2*)&Bp[(4 * li + k) * 34 + 2 * cp];
        float2 z = make_float2(0.f, 0.f);
        float2 aA = z, bA = z, aB = z, bB = z;              // A: H0 pair, B: H1 pair
        #pragma unroll
        for (int t = 0; t < 10; t++) {
            float2 vo = v[19 - 2*t], ve = v[18 - 2*t];
            aA = f2fma(H0B[t], vo, aA); bA = f2fma(H0A[t], ve, bA);
            aB = f2fma(H1B[t], vo, aB); bB = f2fma(H1A[t], ve, bB);
        }
        float* yb = yh1 + (size_t)bc * 49152;
        int j1 = 16 * tj + cp;
        size_t pix = ((size_t)i1 * 64 + j1) * 2;
        const size_t bs = 8192;
        if (half == 0) {
            float* llb = ll2 + (size_t)bc * 16384;
            int gc = 32 * tj + 2 * cp;
            *(float2*)&llb[(size_t)(2*i1)     * 128 + gc] = aA;   // ll ev=a
            *(float2*)&llb[(size_t)(2*i1 + 1) * 128 + gc] = bA;   // ll od=b
            float a = SQ2F*bB.x, b = SQ2F*bB.y, c = SQ2F*aB.x, d = SQ2F*aB.y; // lh ev=b,od=a
            *(float2*)&yb[0*bs + pix] = make_float2(a-d, b+c);
            *(float2*)&yb[5*bs + pix] = make_float2(a+d, b-c);
        } else {
            float a = SQ2F*bB.x, b = SQ2F*bB.y, c = SQ2F*aB.x, d = SQ2F*aB.y; // hh ev=b,od=a
            *(float2*)&yb[1*bs + pix] = make_float2(a-d, b+c);
            *(float2*)&yb[4*bs + pix] = make_float2(a+d, b-c);
            a = SQ2F*aA.x; b = SQ2F*aA.y; c = SQ2F*bA.x; d = SQ2F*bA.y;       // hl ev=a,od=b
            *(float2*)&yb[2*bs + pix] = make_float2(a-d, b+c);
            *(float2*)&yb[3*bs + pix] = make_float2(a+d, b-c);
        }
    }
}

// ---------------------------------------------------------------------------
// Level 3: rowdfilt + coldfilt x4 + bands. Staging now via 16B DMA into a
// single LDS array (pitch 84 = 21 quads -> flat u<->S[4u] mapping), with
// clamped columns + LDS reflection fix (every block is a column-edge block
// when nbj==2). Padded to 1792 units; overflow lands in the Lo region,
// which rowdfilt overwrites after the barrier before any read.
// ---------------------------------------------------------------------------
#define X2(r,c)  S2[(r)*84 + (c)]
#define LO3(r,c) S2[6720 + (r)*34 + (c)]
#define HI3(r,c) S2[9440 + (r)*34 + (c)]

__global__ __launch_bounds__(256) void level_fused(
    const float* __restrict__ X,
    float* __restrict__ llout,
    float* __restrict__ yh,
    int R, int C, int nbi, int nbj)
{
    __shared__ __align__(16) float S2[12160];

    int tid = threadIdx.x;
    int bx  = blockIdx.x;
    int tj = bx % nbj; int ti = (bx / nbj) % nbi; int bc = bx / (nbj * nbi);
    int i0 = ti * 16, j0 = tj * 16;
    int gr0 = 4 * i0 - 8, gc0 = 4 * j0 - 8;     // gc0 % 4 == 0 -> aligned DMA
    const float* Xb = X + (size_t)bc * R * C;
    const int lane = tid & 63;

    // stage 0: 16B DMA, 80x84 tile (1680 real units, padded to 1792 = 7 iters)
    for (int u = tid; u < 1792; u += 256) {
        int r = u / 21, q = u - 21 * r;
        int rr = symref(gr0 + r, R);            // r<=85 -> arg<=141<2R ok
        int g  = gc0 + 4 * q;
        g = (g < 0) ? 0 : ((g > C - 4) ? (C - 4) : g);
        gload_lds16(Xb + (size_t)rr * C + g, &S2[4 * (u - lane)]);
    }
    __syncthreads();

    // column reflection fix (left edge when gc0<0, right edge when gc0+80>C)
    int cl = (gc0 < 0) ? -gc0 : 0;                           // 8 or 0
    int cr = (gc0 + 80 > C) ? (C - gc0) : 80;                // 72 or 80
    if (cl > 0) {
        for (int p = tid; p < 640; p += 256) {               // 80 x 8
            int r = p >> 3, c = p & 7;
            X2(r, c) = X2(r, (-1 - 2 * gc0) - c);
        }
    }
    if (cr < 80) {
        for (int p = tid; p < 640; p += 256) {               // 80 x 8
            int r = p >> 3, c = cr + (p & 7);
            X2(r, c) = X2(r, (2 * C - 1 - 2 * gc0) - c);
        }
    }
    if (cl > 0 || cr < 80) __syncthreads();

    // rowdfilt: b128 window reads, float2 writes
    for (int p = tid; p < 1280; p += 256) {                  // 16 n x 80 rows
        int nl = p / 80, r = p - nl * 80;
        const float* xr = &X2(r, 4 * nl);
        float4 q0 = *(const float4*)&xr[0];
        float4 q1 = *(const float4*)&xr[4];
        float4 q2 = *(const float4*)&xr[8];
        float4 q3 = *(const float4*)&xr[12];
        float4 q4 = *(const float4*)&xr[16];
        float v[20] = {q0.x,q0.y,q0.z,q0.w, q1.x,q1.y,q1.z,q1.w, q2.x,q2.y,q2.z,q2.w,
                       q3.x,q3.y,q3.z,q3.w, q4.x,q4.y,q4.z,q4.w};
        float aLo = 0.f, bLo = 0.f, aHi = 0.f, bHi = 0.f;
        #pragma unroll
        for (int t = 0; t < 10; t++) {
            float vo = v[19 - 2*t], ve = v[18 - 2*t];
            aLo = fmaf(H0B[t], vo, aLo); bLo = fmaf(H0A[t], ve, bLo);
            aHi = fmaf(H1B[t], vo, aHi); bHi = fmaf(H1A[t], ve, bHi);
        }
        *(float2*)&LO3(r, 2 * nl) = make_float2(aLo, bLo);
        *(float2*)&HI3(r, 2 * nl) = make_float2(bHi, aHi);
    }
    __syncthreads();

    // coldfilt + bands: col-pair per thread via b64 reads, in-thread q2c
    int R4 = R >> 2, Wq = C >> 2, C2 = C >> 1;
    int lj = tid & 15, li = tid >> 4;
    int i = i0 + li, j = j0 + lj;

    float2 vl[20], vh[20];
    #pragma unroll
    for (int k = 0; k < 20; k++) {
        vl[k] = *(const float2*)&LO3(4 * li + k, 2 * lj);
        vh[k] = *(const float2*)&HI3(4 * li + k, 2 * lj);
    }
    float2 z = make_float2(0.f, 0.f);
    float2 a_ll = z, b_ll = z, a_lh = z, b_lh = z;
    float2 a_hl = z, b_hl = z, a_hh = z, b_hh = z;
    #pragma unroll
    for (int t = 0; t < 10; t++) {
        float2 vo_l = vl[19 - 2*t], ve_l = vl[18 - 2*t];
        float2 vo_h = vh[19 - 2*t], ve_h = vh[18 - 2*t];
        a_ll = f2fma(H0B[t], vo_l, a_ll); b_ll = f2fma(H0A[t], ve_l, b_ll);
        a_lh = f2fma(H1B[t], vo_l, a_lh); b_lh = f2fma(H1A[t], ve_l, b_lh);
        a_hl = f2fma(H0B[t], vo_h, a_hl); b_hl = f2fma(H0A[t], ve_h, b_hl);
        a_hh = f2fma(H1B[t], vo_h, a_hh); b_hh = f2fma(H1A[t], ve_h, b_hh);
    }

    float* llb = llout + (size_t)bc * (R >> 1) * C2;
    *(float2*)&llb[(size_t)(2*i)   * C2 + 2*j] = a_ll;      // ll ev=a
    *(float2*)&llb[(size_t)(2*i+1) * C2 + 2*j] = b_ll;      // ll od=b

    float* yb = yh + (size_t)bc * 6 * R4 * Wq * 2;
    size_t pix = ((size_t)i * Wq + j) * 2;
    size_t bs  = (size_t)R4 * Wq * 2;
    { float a = SQ2F*b_lh.x, b = SQ2F*b_lh.y, c = SQ2F*a_lh.x, d = SQ2F*a_lh.y;
      *(float2*)&yb[0*bs + pix] = make_float2(a-d, b+c);
      *(float2*)&yb[5*bs + pix] = make_float2(a+d, b-c); }
    { float a = SQ2F*b_hh.x, b = SQ2F*b_hh.y, c = SQ2F*a_hh.x, d = SQ2F*a_hh.y;
      *(float2*)&yb[1*bs + pix] = make_float2(a-d, b+c);
      *(float2*)&yb[4*bs + pix] = make_float2(a+d, b-c); }
    { float a = SQ2F*a_hl.x, b = SQ2F*a_hl.y, c = SQ2F*b_hl.x, d = SQ2F*b_hl.y;
      *(float2*)&yb[2*bs + pix] = make_float2(a-d, b+c);
      *(float2*)&yb[3*bs + pix] = make_float2(a+d, b-c); }
}

extern "C" void kernel_launch(void* const* d_in, const int* in_sizes, int n_in,
                              void* d_out, int out_size, void* d_ws, size_t ws_size,
                              hipStream_t stream) {
    const float* x = (const float*)d_in[0];
    float* out = (float*)d_out;

    const int BC = 8 * 16;  // 128

    float* out_ll  = out;                        // 128*64*64
    float* out_yh0 = out + 524288;               // 128*6*128*128*2
    float* out_yh1 = out + 25690112;             // 128*6*64*64*2
    float* out_yh2 = out + 31981568;             // 128*6*32*32*2

    float* ll2 = (float*)d_ws;                   // 128*128*128 floats = 8 MiB

    // fused levels 1+2: x -> yh0, yh1, ll2
    dtcwt_l12<<<BC * 32, 512, 0, stream>>>(x, out_yh0, out_yh1, ll2);

    // level 3: ll2(128x128) -> yh2, final ll(64x64)
    level_fused<<<BC * 4, 256, 0, stream>>>(ll2, out_ll, out_yh2, 128, 128, 2, 2);
}

// Round 7
// 181.991 us; speedup vs baseline: 1.1521x; 1.0083x over previous
//
#include <hip/hip_runtime.h>

#define SQ2F 0.70710678118654752440f

// Filter taps are compile-time constants (reference _filters() is deterministic;
// float literals round identically to np.float32). Zeros fold out of FMA chains.
static constexpr float H0O[5] = {-0.05f, 0.25f, 0.6f, 0.25f, -0.05f};
static constexpr float H1O[7] = {(float)(-3.0/280.0), (float)(3.0/56.0), (float)(73.0/280.0),
                                 (float)(-17.0/28.0), (float)(73.0/280.0), (float)(3.0/56.0),
                                 (float)(-3.0/280.0)};
static constexpr float H0A[10] = {0.03516384f, 0.0f, -0.08832942f, 0.23389032f, 0.76027237f,
                                  0.5875183f, 0.0f, -0.11430184f, 0.0f, 0.0f};
static constexpr float H0B[10] = {0.0f, 0.0f, -0.11430184f, 0.0f, 0.5875183f,
                                  0.76027237f, 0.23389032f, -0.08832942f, 0.0f, 0.03516384f};
static constexpr float H1A[10] = {0.0f, 0.0f, -0.11430184f, 0.0f, 0.5875183f,
                                  -0.76027237f, 0.23389032f, 0.08832942f, 0.0f, -0.03516384f};
static constexpr float H1B[10] = {-0.03516384f, 0.0f, 0.08832942f, 0.23389032f, -0.76027237f,
                                  0.5875183f, 0.0f, -0.11430184f, 0.0f, 0.0f};

__device__ __forceinline__ int symref(int t, int L) {
    if (t < 0) t = -1 - t;
    if (t >= L) t = 2 * L - 1 - t;
    return t;
}

// async global->LDS, 16 B (dwordx4) per lane — the HW-VERIFIED wide variant
// (m97: emits global_load_lds_dwordx4; lane l writes lds_base + l*16).
// Wave-uniform LDS base, 16B-aligned global address. Partial-wave (exec-masked)
// calls are safe: masked lanes drop their write (proven in the R5 baseline's
// 4368-unit loop with a partial tail wave). (12B variant corrupts — never use.)
__device__ __forceinline__ void gload_lds16(const float* g, float* lds) {
    __builtin_amdgcn_global_load_lds(
        (const __attribute__((address_space(1))) void*)g,
        (__attribute__((address_space(3))) void*)lds, 16, 0, 0);
}

__device__ __forceinline__ float2 f2add(float2 a, float2 b) { return make_float2(a.x + b.x, a.y + b.y); }
__device__ __forceinline__ float2 f2fma(float s, float2 a, float2 b) {
    return make_float2(fmaf(s, a.x, b.x), fmaf(s, a.y, b.y));
}
__device__ __forceinline__ float2 f2s(float s, float2 a) { return make_float2(s * a.x, s * a.y); }

// symmetric 7-tap (H1O) over 7 float2 samples: sum_t H1O[t]*v[6-t]
__device__ __forceinline__ float2 f2sym7(float2 a, float2 b, float2 c, float2 d,
                                         float2 e, float2 f, float2 g) {
    float2 r = f2s(H1O[3], d);
    r = f2fma(H1O[0], f2add(a, g), r);
    r = f2fma(H1O[1], f2add(b, f), r);
    r = f2fma(H1O[2], f2add(c, e), r);
    return r;
}
// symmetric 5-tap (H0O) over 5 float2 samples
__device__ __forceinline__ float2 f2sym5(float2 a, float2 b, float2 c, float2 d, float2 e) {
    float2 r = f2s(H0O[2], c);
    r = f2fma(H0O[0], f2add(a, e), r);
    r = f2fma(H0O[1], f2add(b, d), r);
    return r;
}
// symmetric 5-tap over float4 lanes (4 columns at once)
__device__ __forceinline__ float4 f4sym5(float4 a, float4 b, float4 c, float4 d, float4 e) {
    float4 r;
    r.x = fmaf(H0O[0], a.x + e.x, fmaf(H0O[1], b.x + d.x, H0O[2] * c.x));
    r.y = fmaf(H0O[0], a.y + e.y, fmaf(H0O[1], b.y + d.y, H0O[2] * c.y));
    r.z = fmaf(H0O[0], a.z + e.z, fmaf(H0O[1], b.z + d.z, H0O[2] * c.z));
    r.w = fmaf(H0O[0], a.w + e.w, fmaf(H0O[1], b.w + d.w, H0O[2] * c.w));
    return r;
}

// ---------------------------------------------------------------------------
// Fused levels 1+2. Block = 512 threads; covers x core rows [32ti,32ti+32),
// cols [64tj,64tj+64). Produces yh0 (16x32), yh1 (8x16), ll2 (16x32).
// LDS overlays (46.9 KB -> 3 blocks/CU):
//   S[    0.. 4784) : Xs 52x92 (pitch 92, col base 64tj-12: 16B-aligned DMA)
//                     -> reused as Ls 48x84 after stage 1
//   S[ 4784.. 9152) : Los 52x84 -> after stage 2a, LO2/HI2 48x34 each
//   S[ 9152..11736) : His 38x68
// Pitch 92 = 23 quads (odd) keeps lane->bank-quad histograms uniform for the
// lanes-vary-row reads; pitch 88 would alias to 4 even quads (2x conflict).
// Staging: ONE path for all blocks — 16B DMA with per-lane row symref
// (rows contiguous) + column clamp; the 16 column-border blocks then fix
// their 12/16 edge columns by LDS reflection copy (sources are in-tile).
// The halo IS the symmetric extension (factored symmetric FMA forms make
// reflected windows bit-exact), so stages 2-4 never reflect.
// __launch_bounds__(512,6): LDS allows 3 blocks/CU = 24 waves/CU = 6/SIMD;
// cap VGPRs so occupancy is LDS-limited, not VGPR-limited (occupancy probe).
// ---------------------------------------------------------------------------
#define XS(r,c)  S[(r)*92 + (c)]
#define LS(r,c)  S[(r)*84 + (c)]
#define LOS(r,c) S[4784 + (r)*84 + (c)]
#define LO2(r,c) S[4784 + (r)*34 + (c)]
#define HI2(r,c) S[6416 + (r)*34 + (c)]
#define HIS(r,c) S[9152 + (r)*68 + (c)]

__global__ __launch_bounds__(512, 6) void dtcwt_l12(
    const float* __restrict__ x,
    float* __restrict__ yh0,
    float* __restrict__ yh1,
    float* __restrict__ ll2)
{
    __shared__ __align__(16) float S[11736];
    int tid = threadIdx.x, bx = blockIdx.x;
    int tj = bx & 3, ti = (bx >> 2) & 7, bc = bx >> 5;
    const int xr0 = 32 * ti - 10, xc0 = 64 * tj - 12;   // col base ALIGNED (-12)
    const float* xb = x + (size_t)bc * 65536;
    const int lane = tid & 63;

    // ---- stage 0: 16B-DMA of the 52x92 tile, exactly 1196 units (tail wave
    // partial — exec-masked lanes drop their write; their slots land in the
    // Los region which stage 1 fully overwrites before any read).
    for (int u = tid; u < 1196; u += 512) {
        int r = u / 23, q = u - 23 * r;                 // r <= 51
        int rr = symref(xr0 + r, 256);
        int g  = xc0 + 4 * q;
        g = (g < 0) ? 0 : ((g > 252) ? 252 : g);        // stays 16B-aligned
        gload_lds16(xb + (size_t)rr * 256 + g, &S[4 * (u - lane)]);
    }
    __syncthreads();   // drains vmcnt for the DMA

    // column-border blocks: reflect edge cols from in-tile sources (LDS->LDS).
    // tj=0: tile c<->global c-12; c in [0,12) <- src tile col 23-c.
    // tj=3: tile c<->global 180+c; c in [76,92) <- src tile col 151-c (60..75).
    if (tj == 0) {
        for (int p = tid; p < 624; p += 512) {          // 52 x 12
            int r = p / 12, c = p - 12 * r;
            S[r * 92 + c] = S[r * 92 + (23 - c)];
        }
        __syncthreads();
    } else if (tj == 3) {
        for (int p = tid; p < 832; p += 512) {          // 52 x 16
            int r = p >> 4, c = 76 + (p & 15);
            S[r * 92 + c] = S[r * 92 + (151 - c)];
        }
        __syncthreads();
    }

    // ---- stage 1: row filters, 8 outputs/thread, b128 LDS I/O, symmetric taps
    for (int p = tid; p < 520; p += 512) {                  // 52 rows x 10 slots
        int r = p / 10, s = p - r * 10, c8 = 8 * s;
        const float* xr = &XS(r, c8);
        float4 q0 = *(const float4*)&xr[0];
        float4 q1 = *(const float4*)&xr[4];
        float4 q2 = *(const float4*)&xr[8];
        float4 q3 = *(const float4*)&xr[12];
        float u[16] = {q0.x,q0.y,q0.z,q0.w, q1.x,q1.y,q1.z,q1.w,
                       q2.x,q2.y,q2.z,q2.w, q3.x,q3.y,q3.z,q3.w};
        float l[8];
        #pragma unroll
        for (int j = 0; j < 8; j++)
            l[j] = fmaf(H0O[0], u[j+2] + u[j+6],
                   fmaf(H0O[1], u[j+3] + u[j+5], H0O[2] * u[j+4]));
        *(float4*)&LOS(r, c8)     = make_float4(l[0], l[1], l[2], l[3]);
        *(float4*)&LOS(r, c8 + 4) = make_float4(l[4], l[5], l[6], l[7]);
    }
    // hi: window w[j+1..j+7] from 4 quads at c8+8
    for (int p = tid; p < 304; p += 512) {                  // 38 rows x 8 slots
        int r = p >> 3, s = p & 7, c8 = 8 * s;
        const float* xr = &XS(r + 7, c8 + 8);
        float4 q0 = *(const float4*)&xr[0];
        float4 q1 = *(const float4*)&xr[4];
        float4 q2 = *(const float4*)&xr[8];
        float4 q3 = *(const float4*)&xr[12];
        float w[16] = {q0.x,q0.y,q0.z,q0.w, q1.x,q1.y,q1.z,q1.w,
                       q2.x,q2.y,q2.z,q2.w, q3.x,q3.y,q3.z,q3.w};
        float h[8];
        #pragma unroll
        for (int j = 0; j < 8; j++)
            h[j] = fmaf(H1O[0], w[j+1] + w[j+7],
                   fmaf(H1O[1], w[j+2] + w[j+6],
                   fmaf(H1O[2], w[j+3] + w[j+5], H1O[3] * w[j+4])));
        *(float4*)&HIS(r, c8)     = make_float4(h[0], h[1], h[2], h[3]);
        *(float4*)&HIS(r, c8 + 4) = make_float4(h[4], h[5], h[6], h[7]);
    }
    __syncthreads();

    // ---- stage 2b: ll tile, 2 rows x 4 cols per thread, b128 I/O
    for (int p = tid; p < 480; p += 512) {                  // 24 rowpairs x 20 slots
        int rp = p / 20, s = p - rp * 20, c4 = 4 * s;
        const float* l0 = &LOS(2 * rp, c4);
        float4 m0 = *(const float4*)&l0[0];
        float4 m1 = *(const float4*)&l0[84];
        float4 m2 = *(const float4*)&l0[168];
        float4 m3 = *(const float4*)&l0[252];
        float4 m4 = *(const float4*)&l0[336];
        float4 m5 = *(const float4*)&l0[420];
        *(float4*)&LS(2 * rp,     c4) = f4sym5(m0, m1, m2, m3, m4);
        *(float4*)&LS(2 * rp + 1, c4) = f4sym5(m1, m2, m3, m4, m5);
    }
    // ---- stage 2a: yh0, col-pair per thread (b64 reads), in-thread q2c, no shfl
    {
        float* yb = yh0 + (size_t)bc * 196608;
        const size_t bs = 32768;
        int cp = tid & 31, oi = tid >> 5;                   // 32 colpairs x 16 oi
        float2 low[8], hiw[8];
        #pragma unroll
        for (int k = 0; k < 8; k++) {
            low[k] = *(const float2*)&LOS(2 * oi + 7 + k, 2 * cp + 8);
            hiw[k] = *(const float2*)&HIS(2 * oi + k,     2 * cp);
        }
        float2 lhe = f2s(SQ2F, f2sym7(low[0],low[1],low[2],low[3],low[4],low[5],low[6]));
        float2 lho = f2s(SQ2F, f2sym7(low[1],low[2],low[3],low[4],low[5],low[6],low[7]));
        float2 hhe = f2s(SQ2F, f2sym7(hiw[0],hiw[1],hiw[2],hiw[3],hiw[4],hiw[5],hiw[6]));
        float2 hho = f2s(SQ2F, f2sym7(hiw[1],hiw[2],hiw[3],hiw[4],hiw[5],hiw[6],hiw[7]));
        float2 hle = f2s(SQ2F, f2sym5(hiw[1],hiw[2],hiw[3],hiw[4],hiw[5]));
        float2 hlo = f2s(SQ2F, f2sym5(hiw[2],hiw[3],hiw[4],hiw[5],hiw[6]));
        int i0 = 16 * ti + oi, j0 = 32 * tj + cp;
        size_t pix = ((size_t)i0 * 128 + j0) * 2;
        // q2c: a=e.x b=e.y c=o.x d=o.y -> band k (a-d,b+c), band 5-k (a+d,b-c)
        { float a=lhe.x, b=lhe.y, c=lho.x, d=lho.y;
          *(float2*)&yb[0*bs + pix] = make_float2(a-d, b+c);
          *(float2*)&yb[5*bs + pix] = make_float2(a+d, b-c); }
        { float a=hhe.x, b=hhe.y, c=hho.x, d=hho.y;
          *(float2*)&yb[1*bs + pix] = make_float2(a-d, b+c);
          *(float2*)&yb[4*bs + pix] = make_float2(a+d, b-c); }
        { float a=hle.x, b=hle.y, c=hlo.x, d=hlo.y;
          *(float2*)&yb[2*bs + pix] = make_float2(a-d, b+c);
          *(float2*)&yb[3*bs + pix] = make_float2(a+d, b-c); }
    }
    __syncthreads();

    // ---- stage 3: rowdfilt on Ls -> LO2/HI2. b128 window reads; halo in Ls
    // is bit-exactly the symmetric extension, so no reflection path needed.
    for (int p = tid; p < 768; p += 512) {                  // 16 n x 48 rows
        int nl = p / 48, r = p - nl * 48;
        const float* lsr = &LS(r, 4 * nl);
        float4 q0 = *(const float4*)&lsr[0];
        float4 q1 = *(const float4*)&lsr[4];
        float4 q2 = *(const float4*)&lsr[8];
        float4 q3 = *(const float4*)&lsr[12];
        float4 q4 = *(const float4*)&lsr[16];
        float v[20] = {q0.x,q0.y,q0.z,q0.w, q1.x,q1.y,q1.z,q1.w, q2.x,q2.y,q2.z,q2.w,
                       q3.x,q3.y,q3.z,q3.w, q4.x,q4.y,q4.z,q4.w};
        float aLo = 0.f, bLo = 0.f, aHi = 0.f, bHi = 0.f;
        #pragma unroll
        for (int t = 0; t < 10; t++) {
            float vo = v[19 - 2*t], ve = v[18 - 2*t];
            aLo = fmaf(H0B[t], vo, aLo); bLo = fmaf(H0A[t], ve, bLo);
            aHi = fmaf(H1B[t], vo, aHi); bHi = fmaf(H1A[t], ve, bHi);
        }
        *(float2*)&LO2(r, 2*nl) = make_float2(aLo, bLo);   // lowpass : ev=a, od=b
        *(float2*)&HI2(r, 2*nl) = make_float2(bHi, aHi);   // highpass: ev=b, od=a
    }
    __syncthreads();

    // ---- stage 4: coldfilt + q2c -> yh1, ll2. Col-pair per thread (b64),
    // LO2 half (ll+lh) on tid<128, HI2 half (hl+hh) on tid 128..255.
    if (tid < 256) {
        int half = tid >> 7, q = tid & 127;
        int cp = q & 15, li = q >> 4;                       // 16 colpairs x 8 li
        int i1 = 8 * ti + li;
        const float* Bp = half ? &HI2(0, 0) : &LO2(0, 0);
        float2 v[20];
        #pragma unroll
        for (int k = 0; k < 20; k++)
            v[k] = *(const float2*)&Bp[(4 * li + k) * 34 + 2 * cp];
        float2 z = make_float2(0.f, 0.f);
        float2 aA = z, bA = z, aB = z, bB = z;              // A: H0 pair, B: H1 pair
        #pragma unroll
        for (int t = 0; t < 10; t++) {
            float2 vo = v[19 - 2*t], ve = v[18 - 2*t];
            aA = f2fma(H0B[t], vo, aA); bA = f2fma(H0A[t], ve, bA);
            aB = f2fma(H1B[t], vo, aB); bB = f2fma(H1A[t], ve, bB);
        }
        float* yb = yh1 + (size_t)bc * 49152;
        int j1 = 16 * tj + cp;
        size_t pix = ((size_t)i1 * 64 + j1) * 2;
        const size_t bs = 8192;
        if (half == 0) {
            float* llb = ll2 + (size_t)bc * 16384;
            int gc = 32 * tj + 2 * cp;
            *(float2*)&llb[(size_t)(2*i1)     * 128 + gc] = aA;   // ll ev=a
            *(float2*)&llb[(size_t)(2*i1 + 1) * 128 + gc] = bA;   // ll od=b
            float a = SQ2F*bB.x, b = SQ2F*bB.y, c = SQ2F*aB.x, d = SQ2F*aB.y; // lh ev=b,od=a
            *(float2*)&yb[0*bs + pix] = make_float2(a-d, b+c);
            *(float2*)&yb[5*bs + pix] = make_float2(a+d, b-c);
        } else {
            float a = SQ2F*bB.x, b = SQ2F*bB.y, c = SQ2F*aB.x, d = SQ2F*aB.y; // hh ev=b,od=a
            *(float2*)&yb[1*bs + pix] = make_float2(a-d, b+c);
            *(float2*)&yb[4*bs + pix] = make_float2(a+d, b-c);
            a = SQ2F*aA.x; b = SQ2F*aA.y; c = SQ2F*bA.x; d = SQ2F*bA.y;       // hl ev=a,od=b
            *(float2*)&yb[2*bs + pix] = make_float2(a-d, b+c);
            *(float2*)&yb[3*bs + pix] = make_float2(a+d, b-c);
        }
    }
}

// ---------------------------------------------------------------------------
// Level 3: rowdfilt + coldfilt x4 + bands. 512 threads (halves per-thread
// critical path; lf is latency-bound at only 2 blocks/CU). Final coldfilt
// split Lo-half/Hi-half exactly like l12 stage 4.
// ---------------------------------------------------------------------------
#define X2(r,c)  S2[(r)*84 + (c)]
#define LO3(r,c) S2[6720 + (r)*34 + (c)]
#define HI3(r,c) S2[9440 + (r)*34 + (c)]

__global__ __launch_bounds__(512) void level_fused(
    const float* __restrict__ X,
    float* __restrict__ llout,
    float* __restrict__ yh,
    int R, int C, int nbi, int nbj)
{
    __shared__ __align__(16) float S2[12160];

    int tid = threadIdx.x;
    int bx  = blockIdx.x;
    int tj = bx % nbj; int ti = (bx / nbj) % nbi; int bc = bx / (nbj * nbi);
    int i0 = ti * 16, j0 = tj * 16;
    int gr0 = 4 * i0 - 8, gc0 = 4 * j0 - 8;     // gc0 % 4 == 0 -> aligned DMA
    const float* Xb = X + (size_t)bc * R * C;
    const int lane = tid & 63;

    // stage 0: 16B DMA, 80x84 tile = exactly 1680 units (tail wave partial;
    // masked lanes drop their write; all real slots covered).
    for (int u = tid; u < 1680; u += 512) {
        int r = u / 21, q = u - 21 * r;         // r <= 79
        int rr = symref(gr0 + r, R);
        int g  = gc0 + 4 * q;
        g = (g < 0) ? 0 : ((g > C - 4) ? (C - 4) : g);
        gload_lds16(Xb + (size_t)rr * C + g, &S2[4 * (u - lane)]);
    }
    __syncthreads();

    // column reflection fix (left edge when gc0<0, right edge when gc0+80>C)
    int cl = (gc0 < 0) ? -gc0 : 0;                           // 8 or 0
    int cr = (gc0 + 80 > C) ? (C - gc0) : 80;                // 72 or 80
    if (cl > 0) {
        for (int p = tid; p < 640; p += 512) {               // 80 x 8
            int r = p >> 3, c = p & 7;
            X2(r, c) = X2(r, (-1 - 2 * gc0) - c);
        }
    }
    if (cr < 80) {
        for (int p = tid; p < 640; p += 512) {               // 80 x 8
            int r = p >> 3, c = cr + (p & 7);
            X2(r, c) = X2(r, (2 * C - 1 - 2 * gc0) - c);
        }
    }
    if (cl > 0 || cr < 80) __syncthreads();

    // rowdfilt: b128 window reads, float2 writes
    for (int p = tid; p < 1280; p += 512) {                  // 16 n x 80 rows
        int nl = p / 80, r = p - nl * 80;
        const float* xr = &X2(r, 4 * nl);
        float4 q0 = *(const float4*)&xr[0];
        float4 q1 = *(const float4*)&xr[4];
        float4 q2 = *(const float4*)&xr[8];
        float4 q3 = *(const float4*)&xr[12];
        float4 q4 = *(const float4*)&xr[16];
        float v[20] = {q0.x,q0.y,q0.z,q0.w, q1.x,q1.y,q1.z,q1.w, q2.x,q2.y,q2.z,q2.w,
                       q3.x,q3.y,q3.z,q3.w, q4.x,q4.y,q4.z,q4.w};
        float aLo = 0.f, bLo = 0.f, aHi = 0.f, bHi = 0.f;
        #pragma unroll
        for (int t = 0; t < 10; t++) {
            float vo = v[19 - 2*t], ve = v[18 - 2*t];
            aLo = fmaf(H0B[t], vo, aLo); bLo = fmaf(H0A[t], ve, bLo);
            aHi = fmaf(H1B[t], vo, aHi); bHi = fmaf(H1A[t], ve, bHi);
        }
        *(float2*)&LO3(r, 2 * nl) = make_float2(aLo, bLo);  // lowpass : ev=a, od=b
        *(float2*)&HI3(r, 2 * nl) = make_float2(bHi, aHi);  // highpass: ev=b, od=a
    }
    __syncthreads();

    // coldfilt + bands: col-pair per thread via b64 reads, in-thread q2c.
    // Half-split (512 threads): tid<256 -> LO3 (ll + band0/5),
    // tid>=256 -> HI3 (bands 1/4 and 2/3). Same accumulator algebra as
    // l12 stage 4 (A = H0 pair: ev=aA lowpass; B = H1 pair: ev=bB highpass).
    {
        int half = tid >> 8, q8 = tid & 255;
        int lj = q8 & 15, li = q8 >> 4;
        int i = i0 + li, j = j0 + lj;
        const float* Bp = half ? &HI3(0, 0) : &LO3(0, 0);
        float2 v[20];
        #pragma unroll
        for (int k = 0; k < 20; k++)
            v[k] = *(const float2*)&Bp[(4 * li + k) * 34 + 2 * lj];
        float2 z = make_float2(0.f, 0.f);
        float2 aA = z, bA = z, aB = z, bB = z;
        #pragma unroll
        for (int t = 0; t < 10; t++) {
            float2 vo = v[19 - 2*t], ve = v[18 - 2*t];
            aA = f2fma(H0B[t], vo, aA); bA = f2fma(H0A[t], ve, bA);
            aB = f2fma(H1B[t], vo, aB); bB = f2fma(H1A[t], ve, bB);
        }
        int R4 = R >> 2, Wq = C >> 2, C2 = C >> 1;
        float* yb = yh + (size_t)bc * 6 * R4 * Wq * 2;
        size_t pix = ((size_t)i * Wq + j) * 2;
        size_t bs  = (size_t)R4 * Wq * 2;
        if (half == 0) {
            float* llb = llout + (size_t)bc * (R >> 1) * C2;
            *(float2*)&llb[(size_t)(2*i)   * C2 + 2*j] = aA;    // ll ev=a
            *(float2*)&llb[(size_t)(2*i+1) * C2 + 2*j] = bA;    // ll od=b
            float a = SQ2F*bB.x, b = SQ2F*bB.y, c = SQ2F*aB.x, d = SQ2F*aB.y; // lh ev=b,od=a
            *(float2*)&yb[0*bs + pix] = make_float2(a-d, b+c);
            *(float2*)&yb[5*bs + pix] = make_float2(a+d, b-c);
        } else {
            float a = SQ2F*bB.x, b = SQ2F*bB.y, c = SQ2F*aB.x, d = SQ2F*aB.y; // hh ev=b,od=a
            *(float2*)&yb[1*bs + pix] = make_float2(a-d, b+c);
            *(float2*)&yb[4*bs + pix] = make_float2(a+d, b-c);
            a = SQ2F*aA.x; b = SQ2F*aA.y; c = SQ2F*bA.x; d = SQ2F*bA.y;       // hl ev=a,od=b
            *(float2*)&yb[2*bs + pix] = make_float2(a-d, b+c);
            *(float2*)&yb[3*bs + pix] = make_float2(a+d, b-c);
        }
    }
}

extern "C" void kernel_launch(void* const* d_in, const int* in_sizes, int n_in,
                              void* d_out, int out_size, void* d_ws, size_t ws_size,
                              hipStream_t stream) {
    const float* x = (const float*)d_in[0];
    float* out = (float*)d_out;

    const int BC = 8 * 16;  // 128

    float* out_ll  = out;                        // 128*64*64
    float* out_yh0 = out + 524288;               // 128*6*128*128*2
    float* out_yh1 = out + 25690112;             // 128*6*64*64*2
    float* out_yh2 = out + 31981568;             // 128*6*32*32*2

    float* ll2 = (float*)d_ws;                   // 128*128*128 floats = 8 MiB

    // fused levels 1+2: x -> yh0, yh1, ll2
    dtcwt_l12<<<BC * 32, 512, 0, stream>>>(x, out_yh0, out_yh1, ll2);

    // level 3: ll2(128x128) -> yh2, final ll(64x64)
    level_fused<<<BC * 4, 512, 0, stream>>>(ll2, out_ll, out_yh2, 128, 128, 2, 2);
}